// Round 5
// baseline (291.808 us; speedup 1.0000x reference)
//
#include <hip/hip_runtime.h>

#define TSTEPS 4
#define DIM 32
#define BIN_SHIFT 7
#define BIN_W 128            // nodes per bin
#define NBINS_MAX 400        // LDS sizing; runtime nbins = ceil(N/128) = 391
#define CAPB 2560            // max edges/bin: lambda=2048, ~11 sigma headroom
#define STAGE 16             // staged records per bin in pass 1
#define P1_BLOCKS 64

// ---- pass 1: bin edges {src,dst} by dst>>7 with LDS staging; flush full
// 64B groups of 8 so every HBM line is written whole by a single thread ----
__global__ __launch_bounds__(256) void bin_kernel(
    const int* __restrict__ ei, int* __restrict__ gcnt, int2* __restrict__ bins,
    int E, int nbins, int chunk) {
    __shared__ int2 stage[NBINS_MAX][STAGE];  // 51.2 KB
    __shared__ int scnt[NBINS_MAX];
    int tid = threadIdx.x;
    for (int b = tid; b < nbins; b += 256) scnt[b] = 0;
    __syncthreads();
    int beg = blockIdx.x * chunk;
    int end = min(beg + chunk, E);
    for (int base = beg; base < end; base += 256) {
        int e = base + tid;
        int pending = 0; int2 r; int bin = 0;
        if (e < end) {
            r.x = ei[e];        // src
            r.y = ei[E + e];    // dst
            bin = r.y >> BIN_SHIFT;
            int slot = atomicAdd(&scnt[bin], 1);
            if (slot < STAGE) stage[bin][slot] = r;
            else pending = 1;   // rare staging overflow -> direct append
        }
        __syncthreads();
        if (pending) {
            int pos = atomicAdd(&gcnt[bin], 1);
            if (pos < CAPB) bins[bin * CAPB + pos] = r;
        }
        // flush full groups of 8 (one thread owns a bin during flush)
        for (int b = tid; b < nbins; b += 256) {
            int c = min(scnt[b], STAGE);
            int f = c & ~7;
            if (f > 0) {
                int gpos = atomicAdd(&gcnt[b], f);
                for (int j = 0; j < f; j++)
                    if (gpos + j < CAPB) bins[b * CAPB + gpos + j] = stage[b][j];
                int rmd = c - f;
                for (int j = 0; j < rmd; j++) stage[b][j] = stage[b][f + j];
                scnt[b] = rmd;
            } else {
                scnt[b] = c;  // clamp any overflowed count
            }
        }
        __syncthreads();
    }
    // final drain (partial groups; bounded, negligible churn)
    for (int b = tid; b < nbins; b += 256) {
        int c = min(scnt[b], STAGE);
        if (c > 0) {
            int gpos = atomicAdd(&gcnt[b], c);
            for (int j = 0; j < c; j++)
                if (gpos + j < CAPB) bins[b * CAPB + gpos + j] = stage[b][j];
        }
    }
}

// ---- pass 2: one block per bin. LDS histogram -> CSR (16B-aligned segments),
// write sorted src recs + offs + deg + dinv, all coalesced ----
__global__ __launch_bounds__(256) void csr_kernel(
    const int* __restrict__ gcnt, const int2* __restrict__ bins,
    int* __restrict__ rec, int* __restrict__ offs, int* __restrict__ deg,
    float* __restrict__ dinv, int* __restrict__ cursor, int N) {
    __shared__ int2 raw[CAPB];                 // 20.5 KB
    __shared__ int sorted[CAPB + 3 * BIN_W];   // 11.8 KB
    __shared__ int hist[BIN_W], cur[BIN_W], loff[BIN_W];
    __shared__ int sbase, stot;
    int bin = blockIdx.x;
    int tid = threadIdx.x;
    int nodeBase = bin << BIN_SHIFT;
    int c = min(gcnt[bin], CAPB);
    for (int i = tid; i < c; i += 256) raw[i] = bins[bin * CAPB + i];
    for (int i = tid; i < BIN_W; i += 256) { hist[i] = 0; cur[i] = 0; }
    __syncthreads();
    for (int i = tid; i < c; i += 256) atomicAdd(&hist[raw[i].y & (BIN_W - 1)], 1);
    __syncthreads();
    if (tid == 0) {
        int run = 0;
        for (int i = 0; i < BIN_W; i++) {
            loff[i] = run;
            run += (hist[i] + 3) & ~3;  // pad each node segment to 16B
        }
        stot = run;
        sbase = atomicAdd(cursor, run);
    }
    __syncthreads();
    int gbase = sbase;
    for (int i = tid; i < c; i += 256) {
        int ln = raw[i].y & (BIN_W - 1);
        int p = atomicAdd(&cur[ln], 1);
        sorted[loff[ln] + p] = raw[i].x;
    }
    __syncthreads();
    for (int i = tid; i < BIN_W; i += 256) {
        int n = nodeBase + i;
        if (n < N) {
            offs[n] = gbase + loff[i];
            deg[n] = hist[i];
            dinv[n] = rsqrtf((float)hist[i] + 1.0f);
        }
    }
    int tot = stot;
    for (int i = tid; i < tot; i += 256) rec[gbase + i] = sorted[i];
}

// ---- fused gather(raw s) + self-loop + W-transform + mean + IF scan + z_new ----
// 32 lanes/node (within one half-wave). lane l = (t=l>>3, q=l&7) owns a float4.
__global__ __launch_bounds__(256) void gather_kernel(
    const int* __restrict__ rec, const int* __restrict__ offs, const int* __restrict__ deg,
    const float* __restrict__ s, const float* __restrict__ Wm,
    const float* __restrict__ dinv, const float* __restrict__ z,
    float* __restrict__ out, int N) {
    __shared__ float sW[1024];            // W row-major [d][f]
    __shared__ float aggS[4][2][4][36];   // [wave][nodeInWave][t][32+pad] (16B-aligned rows)
    int tid = threadIdx.x;
    for (int i = tid; i < 1024; i += 256) sW[i] = Wm[i];
    __syncthreads();
    int gid = blockIdx.x * 256 + tid;
    int n = gid >> 5;
    if (n >= N) return;
    int wl = tid & 63;
    int half = wl >> 5;
    int l = wl & 31;
    int t = l >> 3;
    int q = l & 7;
    int wv = tid >> 6;
    const float* sp = s + (size_t)t * N * DIM + 4 * q;

    int beg = offs[n];      // 16B-aligned (padded CSR)
    int cntn = deg[n];
    float dn = dinv[n];

    float4 acc = make_float4(0.f, 0.f, 0.f, 0.f);
    int i = 0;
    for (; i + 4 <= cntn; i += 4) {
        int4 s4 = *(const int4*)(rec + beg + i);
        float n0 = dinv[s4.x] * dn;
        float n1 = dinv[s4.y] * dn;
        float n2 = dinv[s4.z] * dn;
        float n3 = dinv[s4.w] * dn;
        float4 p0 = *(const float4*)(sp + (size_t)s4.x * DIM);
        float4 p1 = *(const float4*)(sp + (size_t)s4.y * DIM);
        float4 p2 = *(const float4*)(sp + (size_t)s4.z * DIM);
        float4 p3 = *(const float4*)(sp + (size_t)s4.w * DIM);
        acc.x += n0 * p0.x + n1 * p1.x + n2 * p2.x + n3 * p3.x;
        acc.y += n0 * p0.y + n1 * p1.y + n2 * p2.y + n3 * p3.y;
        acc.z += n0 * p0.z + n1 * p1.z + n2 * p2.z + n3 * p3.z;
        acc.w += n0 * p0.w + n1 * p1.w + n2 * p2.w + n3 * p3.w;
    }
    for (; i < cntn; i++) {
        int s0 = rec[beg + i];
        float n0 = dinv[s0] * dn;
        float4 p0 = *(const float4*)(sp + (size_t)s0 * DIM);
        acc.x += n0 * p0.x;
        acc.y += n0 * p0.y;
        acc.z += n0 * p0.z;
        acc.w += n0 * p0.w;
    }
    // self loop on raw features
    {
        float d2 = dn * dn;
        float4 ps = *(const float4*)(sp + (size_t)n * DIM);
        acc.x += d2 * ps.x;
        acc.y += d2 * ps.y;
        acc.z += d2 * ps.z;
        acc.w += d2 * ps.w;
    }
    // ---- transform: x[t][f] = sum_d agg[t][d] * W[d][f]  (node-local, via LDS) ----
    float* ag = &aggS[wv][half][t][0];
    *(float4*)(ag + 4 * q) = acc;
    __builtin_amdgcn_wave_barrier();  // same-wave LDS RAW; HW-ordered, pin compiler
    float4 xr = make_float4(0.f, 0.f, 0.f, 0.f);
#pragma unroll
    for (int dq = 0; dq < 8; dq++) {
        float4 a4 = *(const float4*)(ag + 4 * dq);
        float4 w0 = *(const float4*)(sW + (4 * dq + 0) * 32 + 4 * q);
        float4 w1 = *(const float4*)(sW + (4 * dq + 1) * 32 + 4 * q);
        float4 w2 = *(const float4*)(sW + (4 * dq + 2) * 32 + 4 * q);
        float4 w3 = *(const float4*)(sW + (4 * dq + 3) * 32 + 4 * q);
        xr.x += a4.x * w0.x + a4.y * w1.x + a4.z * w2.x + a4.w * w3.x;
        xr.y += a4.x * w0.y + a4.y * w1.y + a4.z * w2.y + a4.w * w3.y;
        xr.z += a4.x * w0.z + a4.y * w1.z + a4.z * w2.z + a4.w * w3.z;
        xr.w += a4.x * w0.w + a4.y * w1.w + a4.z * w2.w + a4.w * w3.w;
    }
    // transpose (t,q) -> lane q holds x[t] for its 4 features
    float4 xs[TSTEPS];
#pragma unroll
    for (int tt = 0; tt < TSTEPS; tt++) {
        int srcLane = half * 32 + tt * 8 + q;
        xs[tt].x = __shfl(xr.x, srcLane, 64);
        xs[tt].y = __shfl(xr.y, srcLane, 64);
        xs[tt].z = __shfl(xr.z, srcLane, 64);
        xs[tt].w = __shfl(xr.w, srcLane, 64);
    }
    if (l < 8) {
        float4 y;
        y.x = (xs[0].x + xs[1].x + xs[2].x + xs[3].x) * 0.25f;
        y.y = (xs[0].y + xs[1].y + xs[2].y + xs[3].y) * 0.25f;
        y.z = (xs[0].z + xs[1].z + xs[2].z + xs[3].z) * 0.25f;
        y.w = (xs[0].w + xs[1].w + xs[2].w + xs[3].w) * 0.25f;
        float4 v = make_float4(0.f, 0.f, 0.f, 0.f);
        int colBase = n * 32 + q * 4;
#pragma unroll
        for (int tt = 0; tt < TSTEPS; tt++) {
            float4 o;
            v.x += xs[tt].x; o.x = (v.x >= 1.0f) ? 1.0f : 0.0f; v.x -= o.x;
            v.y += xs[tt].y; o.y = (v.y >= 1.0f) ? 1.0f : 0.0f; v.y -= o.y;
            v.z += xs[tt].z; o.z = (v.z >= 1.0f) ? 1.0f : 0.0f; v.z -= o.z;
            v.w += xs[tt].w; o.w = (v.w >= 1.0f) ? 1.0f : 0.0f; v.w -= o.w;
            *(float4*)(out + (size_t)tt * N * 32 + colBase) = o;
        }
        float4 zv = *(const float4*)(z + colBase);
        float4 zn;
        zn.x = zv.x + y.x;
        zn.y = zv.y + y.y;
        zn.z = zv.z + y.z;
        zn.w = zv.w + y.w;
        *(float4*)(out + (size_t)TSTEPS * N * 32 + colBase) = zn;
    }
}

extern "C" void kernel_launch(void* const* d_in, const int* in_sizes, int n_in,
                              void* d_out, int out_size, void* d_ws, size_t ws_size,
                              hipStream_t stream) {
    const float* s_seq = (const float*)d_in[0];
    const float* z_seq = (const float*)d_in[1];
    const float* W     = (const float*)d_in[2];
    const int*   ei    = (const int*)d_in[3];
    float* out = (float*)d_out;

    const int N = in_sizes[1] / DIM;   // 50000
    const int E = in_sizes[3] / 2;     // 800000
    const int nbins = (N + BIN_W - 1) >> BIN_SHIFT;  // 391

    // ws layout (ints): gcnt[400] | cursor[4] | offs[N] | deg[N] | dinv[N] |
    //                   bins[400*CAPB int2] | rec[E + 4N]
    int* w = (int*)d_ws;
    int*   gcnt   = w;                    w += NBINS_MAX;
    int*   cursor = w;                    w += 4;
    int*   offs   = w;                    w += N;
    int*   deg    = w;                    w += N;
    float* dinv   = (float*)w;            w += N;
    int2*  bins   = (int2*)w;             w += NBINS_MAX * CAPB * 2;
    int*   rec    = w;                    // (E + 4N)*4 B = 4 MB

    hipMemsetAsync(gcnt, 0, (NBINS_MAX + 4) * sizeof(int), stream);

    int chunk = (E + P1_BLOCKS - 1) / P1_BLOCKS;
    bin_kernel<<<P1_BLOCKS, 256, 0, stream>>>(ei, gcnt, bins, E, nbins, chunk);
    csr_kernel<<<nbins, 256, 0, stream>>>(gcnt, bins, rec, offs, deg, dinv, cursor, N);
    gather_kernel<<<(N * 32 + 255) / 256, 256, 0, stream>>>(rec, offs, deg, s_seq, W,
                                                            dinv, z_seq, out, N);
}

// Round 6
// 225.679 us; speedup vs baseline: 1.2930x; 1.2930x over previous
//
#include <hip/hip_runtime.h>

#define TSTEPS 4
#define DIM 32
#define NG 4        // sub-bucket groups (blockIdx & 3)
#define GCAP 16     // slots per group = one 64B line
#define SCAP 32     // per-node spill capacity (expected use ~0)

// ---- fused: edge bucketing (blocks [0,fillBlocks)) + xw GEMM (rest) ----
// rec[node*64 + g*16 + slot]: each 64B line is written only by blocks with
// blockIdx&3 == g (~1-2 XCDs under round-robin dispatch) -> no cross-XCD
// partial-line writeback churn.
__global__ __launch_bounds__(256) void fillxw_kernel(
    const int* __restrict__ ei, int* __restrict__ cnt4, int* __restrict__ scnt,
    int* __restrict__ sbuf, int* __restrict__ rec,
    const float* __restrict__ s, const float* __restrict__ W, float* __restrict__ xwp,
    int E, int rows, int N, int fillBlocks) {
    __shared__ float sW[32][33];
    __shared__ float sS[32][33];
    if ((int)blockIdx.x < fillBlocks) {
        int e = blockIdx.x * 256 + threadIdx.x;
        if (e < E) {
            int src = ei[e];
            int dst = ei[E + e];
            int g = blockIdx.x & (NG - 1);
            int slot = atomicAdd(&cnt4[dst * NG + g], 1);
            if (slot < GCAP) {
                rec[dst * (NG * GCAP) + g * GCAP + slot] = src;
            } else {
                int ss = atomicAdd(&scnt[dst], 1);
                if (ss < SCAP) sbuf[dst * SCAP + ss] = src;
            }
        }
        return;
    }
    // xw = s @ W, stored node-major: xwp[n*128 + t*32 + c]
    int tid = threadIdx.x;
    for (int i = tid; i < 1024; i += 256) sW[i >> 5][i & 31] = W[i];
    int rowBase = (blockIdx.x - fillBlocks) * 32;
    for (int i = tid; i < 1024; i += 256) {
        int r = rowBase + (i >> 5);
        sS[i >> 5][i & 31] = (r < rows) ? s[r * 32 + (i & 31)] : 0.0f;
    }
    __syncthreads();
    int c = tid & 31;
    for (int rl = tid >> 5; rl < 32; rl += 8) {
        float acc = 0.0f;
#pragma unroll
        for (int k = 0; k < 32; k++) acc += sS[rl][k] * sW[k][c];
        int r = rowBase + rl;
        if (r < rows) {
            int t = r / N;
            int n = r - t * N;
            xwp[n * 128 + t * 32 + c] = acc;
        }
    }
}

// ---- dinv[n] = rsqrt(true_degree + 1); true degree = sum of raw group counters ----
__global__ void dinv_kernel(const int* __restrict__ cnt4, float* __restrict__ dinv, int N) {
    int n = blockIdx.x * blockDim.x + threadIdx.x;
    if (n < N) {
        int4 c = *(const int4*)(cnt4 + n * 4);
        dinv[n] = rsqrtf((float)(c.x + c.y + c.z + c.w) + 1.0f);
    }
}

// ---- fused gather + self-loop + mean + IF scan + z_new ----
// 32 lanes per node; lane l owns (t = l>>3, q = l&7) as a float4 of xwp.
__global__ __launch_bounds__(256) void gather_kernel(
    const int* __restrict__ rec, const int* __restrict__ cnt4,
    const int* __restrict__ scnt, const int* __restrict__ sbuf,
    const float* __restrict__ xwp, const float* __restrict__ dinv,
    const float* __restrict__ z, float* __restrict__ out, int N) {
    int gid = blockIdx.x * 256 + threadIdx.x;
    int n = gid >> 5;
    if (n >= N) return;
    int wl = threadIdx.x & 63;
    int half = wl >> 5;
    int l = wl & 31;
    int q = l & 7;
    int l4 = l * 4;

    float dn = dinv[n];
    int4 c4 = *(const int4*)(cnt4 + n * 4);
    int cg_arr[NG] = {c4.x, c4.y, c4.z, c4.w};
    const int* rb = rec + n * (NG * GCAP);

    float4 acc = make_float4(0.f, 0.f, 0.f, 0.f);
#pragma unroll
    for (int g = 0; g < NG; g++) {
        int cg = min(cg_arr[g], GCAP);
        for (int i = 0; i < cg; i += 4) {
            int4 s4 = *(const int4*)(rb + g * GCAP + i);  // 16B-aligned
            int rem = cg - i;
            int i0 = s4.x;
            int i1 = (rem > 1) ? s4.y : i0;  // clamp: tail slots hold poison
            int i2 = (rem > 2) ? s4.z : i0;
            int i3 = (rem > 3) ? s4.w : i0;
            float n0 = dinv[i0] * dn;
            float n1 = (rem > 1) ? dinv[i1] * dn : 0.f;
            float n2 = (rem > 2) ? dinv[i2] * dn : 0.f;
            float n3 = (rem > 3) ? dinv[i3] * dn : 0.f;
            float4 p0 = *(const float4*)(xwp + (long)i0 * 128 + l4);
            float4 p1 = *(const float4*)(xwp + (long)i1 * 128 + l4);
            float4 p2 = *(const float4*)(xwp + (long)i2 * 128 + l4);
            float4 p3 = *(const float4*)(xwp + (long)i3 * 128 + l4);
            acc.x += n0 * p0.x + n1 * p1.x + n2 * p2.x + n3 * p3.x;
            acc.y += n0 * p0.y + n1 * p1.y + n2 * p2.y + n3 * p3.y;
            acc.z += n0 * p0.z + n1 * p1.z + n2 * p2.z + n3 * p3.z;
            acc.w += n0 * p0.w + n1 * p1.w + n2 * p2.w + n3 * p3.w;
        }
    }
    // spill drain (expected empty; correctness path for bucket overflow)
    int sc = min(scnt[n], SCAP);
    for (int i = 0; i < sc; i++) {
        int s0 = sbuf[n * SCAP + i];
        float n0 = dinv[s0] * dn;
        float4 p0 = *(const float4*)(xwp + (long)s0 * 128 + l4);
        acc.x += n0 * p0.x;
        acc.y += n0 * p0.y;
        acc.z += n0 * p0.z;
        acc.w += n0 * p0.w;
    }
    // self loop: + xwp[n] * dinv[n]^2
    {
        float d2 = dn * dn;
        float4 ps = *(const float4*)(xwp + (long)n * 128 + l4);
        acc.x += d2 * ps.x;
        acc.y += d2 * ps.y;
        acc.z += d2 * ps.z;
        acc.w += d2 * ps.w;
    }
    // transpose (t,q) -> lane q holds x[t] for its 4 features
    float4 xs[TSTEPS];
#pragma unroll
    for (int t = 0; t < TSTEPS; t++) {
        int srcLane = half * 32 + t * 8 + q;
        xs[t].x = __shfl(acc.x, srcLane, 64);
        xs[t].y = __shfl(acc.y, srcLane, 64);
        xs[t].z = __shfl(acc.z, srcLane, 64);
        xs[t].w = __shfl(acc.w, srcLane, 64);
    }
    if (l < 8) {
        float4 y;
        y.x = (xs[0].x + xs[1].x + xs[2].x + xs[3].x) * 0.25f;
        y.y = (xs[0].y + xs[1].y + xs[2].y + xs[3].y) * 0.25f;
        y.z = (xs[0].z + xs[1].z + xs[2].z + xs[3].z) * 0.25f;
        y.w = (xs[0].w + xs[1].w + xs[2].w + xs[3].w) * 0.25f;
        float4 v = make_float4(0.f, 0.f, 0.f, 0.f);
        int colBase = n * 32 + q * 4;
#pragma unroll
        for (int t = 0; t < TSTEPS; t++) {
            float4 o;
            v.x += xs[t].x; o.x = (v.x >= 1.0f) ? 1.0f : 0.0f; v.x -= o.x;
            v.y += xs[t].y; o.y = (v.y >= 1.0f) ? 1.0f : 0.0f; v.y -= o.y;
            v.z += xs[t].z; o.z = (v.z >= 1.0f) ? 1.0f : 0.0f; v.z -= o.z;
            v.w += xs[t].w; o.w = (v.w >= 1.0f) ? 1.0f : 0.0f; v.w -= o.w;
            *(float4*)(out + (size_t)t * N * 32 + colBase) = o;
        }
        float4 zv = *(const float4*)(z + colBase);
        float4 zn;
        zn.x = zv.x + y.x;
        zn.y = zv.y + y.y;
        zn.z = zv.z + y.z;
        zn.w = zv.w + y.w;
        *(float4*)(out + (size_t)TSTEPS * N * 32 + colBase) = zn;
    }
}

extern "C" void kernel_launch(void* const* d_in, const int* in_sizes, int n_in,
                              void* d_out, int out_size, void* d_ws, size_t ws_size,
                              hipStream_t stream) {
    const float* s_seq = (const float*)d_in[0];
    const float* z_seq = (const float*)d_in[1];
    const float* W     = (const float*)d_in[2];
    const int*   ei    = (const int*)d_in[3];
    float* out = (float*)d_out;

    const int N = in_sizes[1] / DIM;   // 50000
    const int E = in_sizes[3] / 2;     // 800000
    const int rows = TSTEPS * N;       // 200000

    // ws (ints): cnt4[4N] | scnt[N] | sbuf[32N] | dinv[N] | xwp[rows*32] | rec[64N]
    int* w = (int*)d_ws;
    int*   cnt4 = w;            w += (size_t)N * NG;
    int*   scnt = w;            w += (size_t)N;
    int*   sbuf = w;            w += (size_t)N * SCAP;
    float* dinv = (float*)w;    w += (size_t)N;
    float* xwp  = (float*)w;    w += (size_t)rows * DIM;   // 25.6 MB
    int*   rec  = w;            // N*64*4 = 12.8 MB

    // one contiguous memset covers cnt4 + scnt
    hipMemsetAsync(cnt4, 0, (size_t)N * (NG + 1) * sizeof(int), stream);

    int fillBlocks = (E + 255) / 256;          // 3125
    int xwBlocks   = (rows + 31) / 32;         // 6250
    fillxw_kernel<<<fillBlocks + xwBlocks, 256, 0, stream>>>(
        ei, cnt4, scnt, sbuf, rec, s_seq, W, xwp, E, rows, N, fillBlocks);
    dinv_kernel<<<(N + 255) / 256, 256, 0, stream>>>(cnt4, dinv, N);
    gather_kernel<<<(N * 32 + 255) / 256, 256, 0, stream>>>(rec, cnt4, scnt, sbuf,
                                                            xwp, dinv, z_seq, out, N);
}

// Round 7
// 222.036 us; speedup vs baseline: 1.3142x; 1.0164x over previous
//
#include <hip/hip_runtime.h>

#define TSTEPS 4
#define DIM 32
#define BINW_SHIFT 8          // 256 nodes per coarse bin
#define NB_MAX 256            // max coarse bins (N=50000 -> 196)
#define HB 128                // histogram blocks in K1
#define K3_CH 4096            // edges per K3 block
#define CAPB 4608             // max edges per bin (mean 4096, 8 sigma)

// ---- K1: fused coarse histogram (blocks [0,HB)) + xw GEMM (rest) ----
__global__ __launch_bounds__(256) void histxw_kernel(
    const int* __restrict__ ei, int* __restrict__ ghist,
    const float* __restrict__ s, const float* __restrict__ W, float* __restrict__ xwp,
    int E, int rows, int N, int nb, int hch) {
    __shared__ float sW[32][33];
    __shared__ float sS[32][33];
    __shared__ int lh[NB_MAX];
    int tid = threadIdx.x;
    if ((int)blockIdx.x < HB) {
        for (int b = tid; b < nb; b += 256) lh[b] = 0;
        __syncthreads();
        int beg = blockIdx.x * hch;
        int end = min(beg + hch, E);
        for (int e = beg + tid; e < end; e += 256)
            atomicAdd(&lh[ei[E + e] >> BINW_SHIFT], 1);
        __syncthreads();
        for (int b = tid; b < nb; b += 256)
            if (lh[b]) atomicAdd(&ghist[b], lh[b]);
        return;
    }
    // xw = s @ W, stored node-major: xwp[n*128 + t*32 + c]
    for (int i = tid; i < 1024; i += 256) sW[i >> 5][i & 31] = W[i];
    int rowBase = (blockIdx.x - HB) * 32;
    for (int i = tid; i < 1024; i += 256) {
        int r = rowBase + (i >> 5);
        sS[i >> 5][i & 31] = (r < rows) ? s[r * 32 + (i & 31)] : 0.0f;
    }
    __syncthreads();
    int c = tid & 31;
    for (int rl = tid >> 5; rl < 32; rl += 8) {
        float acc = 0.0f;
#pragma unroll
        for (int k = 0; k < 32; k++) acc += sS[rl][k] * sW[k][c];
        int r = rowBase + rl;
        if (r < rows) {
            int t = r / N;
            int n = r - t * N;
            xwp[n * 128 + t * 32 + c] = acc;
        }
    }
}

// ---- K2: exclusive scan of ghist -> binStart, cursor ----
__global__ __launch_bounds__(256) void scan_kernel(
    const int* __restrict__ ghist, int* __restrict__ binStart,
    int* __restrict__ cursor, int nb) {
    __shared__ int sbuf[256];
    int tid = threadIdx.x;
    int v = (tid < nb) ? ghist[tid] : 0;
    sbuf[tid] = v;
    __syncthreads();
    for (int off = 1; off < 256; off <<= 1) {
        int t = (tid >= off) ? sbuf[tid - off] : 0;
        __syncthreads();
        sbuf[tid] += t;
        __syncthreads();
    }
    if (tid < nb) {
        int excl = sbuf[tid] - v;
        binStart[tid] = excl;
        cursor[tid] = excl;
    }
}

// ---- K3: multisplit — sort each block's chunk by coarse bin in LDS,
// allocate per-bin runs, write bin-grouped edges coalesced ----
__global__ __launch_bounds__(256) void split_kernel(
    const int* __restrict__ ei, int* __restrict__ cursor,
    int2* __restrict__ esorted, int E, int nb) {
    __shared__ int ph[NB_MAX], pscan[NB_MAX], gb[NB_MAX], pcur[NB_MAX];
    __shared__ int2 sbuf[K3_CH];
    int tid = threadIdx.x;
    int beg = blockIdx.x * K3_CH;
    int end = min(beg + K3_CH, E);
    int cnt = end - beg;
    for (int b = tid; b < nb; b += 256) ph[b] = 0;
    __syncthreads();
    int2 r[K3_CH / 256];
    int nk = (cnt + 255) >> 8;
#pragma unroll 4
    for (int k = 0; k < nk; k++) {
        int e = beg + k * 256 + tid;
        if (e < end) {
            r[k].x = ei[e];
            r[k].y = ei[E + e];
            atomicAdd(&ph[r[k].y >> BINW_SHIFT], 1);
        }
    }
    __syncthreads();
    // exclusive scan of ph (256-wide Hillis-Steele)
    {
        int v = (tid < nb) ? ph[tid] : 0;
        int s = v;
        __syncthreads();
        pscan[tid] = s;
        __syncthreads();
        for (int off = 1; off < 256; off <<= 1) {
            int t = (tid >= off) ? pscan[tid - off] : 0;
            __syncthreads();
            pscan[tid] += t;
            __syncthreads();
        }
        if (tid < 256) pscan[tid] -= v;  // exclusive
    }
    __syncthreads();
    for (int b = tid; b < nb; b += 256) {
        pcur[b] = pscan[b];
        gb[b] = ph[b] ? atomicAdd(&cursor[b], ph[b]) : 0;
    }
    __syncthreads();
    for (int k = 0; k < nk; k++) {
        int e = beg + k * 256 + tid;
        if (e < end) {
            int b = r[k].y >> BINW_SHIFT;
            int p = atomicAdd(&pcur[b], 1);
            sbuf[p] = r[k];
        }
    }
    __syncthreads();
    for (int idx = tid; idx < cnt; idx += 256) {
        int2 e = sbuf[idx];
        int b = e.y >> BINW_SHIFT;
        esorted[gb[b] + (idx - pscan[b])] = e;
    }
}

// ---- K4: per-bin exact CSR: counting sort by dst, 16B-padded segments,
// write rec + offs + deg + dinv coalesced ----
__global__ __launch_bounds__(256) void csr_kernel(
    const int* __restrict__ ghist, const int* __restrict__ binStart,
    const int2* __restrict__ esorted, int* __restrict__ rec,
    int* __restrict__ offs, int* __restrict__ deg, float* __restrict__ dinv,
    int* __restrict__ recCursor, int N) {
    __shared__ int sorted[CAPB + 3 * 256];
    __shared__ int lh[256], loff[256], lcur[256];
    __shared__ int sbase, srun;
    int bin = blockIdx.x;
    int tid = threadIdx.x;
    int nodeBase = bin << BINW_SHIFT;
    int ebeg = binStart[bin];
    int cnt = min(ghist[bin], CAPB);
    lh[tid] = 0;
    __syncthreads();
    for (int i = tid; i < cnt; i += 256)
        atomicAdd(&lh[esorted[ebeg + i].y & 255], 1);
    __syncthreads();
    if (tid == 0) {
        int run = 0;
        for (int i = 0; i < 256; i++) {
            loff[i] = run;
            run += (lh[i] + 3) & ~3;  // 16B-align every node segment
        }
        srun = run;
        sbase = atomicAdd(recCursor, run);
    }
    __syncthreads();
    int run = srun, gbase = sbase;
    for (int i = tid; i < run; i += 256) sorted[i] = 0;  // zero pad slots
    lcur[tid] = 0;
    __syncthreads();
    for (int i = tid; i < cnt; i += 256) {
        int2 e = esorted[ebeg + i];
        int ln = e.y & 255;
        int p = atomicAdd(&lcur[ln], 1);
        sorted[loff[ln] + p] = e.x;
    }
    __syncthreads();
    for (int i = tid; i < run; i += 256) rec[gbase + i] = sorted[i];
    int n = nodeBase + tid;
    if (n < N) {
        offs[n] = gbase + loff[tid];
        deg[n] = lh[tid];
        dinv[n] = rsqrtf((float)lh[tid] + 1.0f);
    }
}

// ---- K5: fused gather + self-loop + mean + IF scan + z_new (R6-proven) ----
__global__ __launch_bounds__(256) void gather_kernel(
    const int* __restrict__ rec, const int* __restrict__ offs,
    const int* __restrict__ deg, const float* __restrict__ xwp,
    const float* __restrict__ dinv, const float* __restrict__ z,
    float* __restrict__ out, int N) {
    int gid = blockIdx.x * 256 + threadIdx.x;
    int n = gid >> 5;
    if (n >= N) return;
    int wl = threadIdx.x & 63;
    int half = wl >> 5;
    int l = wl & 31;
    int q = l & 7;
    int l4 = l * 4;

    float dn = dinv[n];
    int beg = offs[n];       // multiple of 4 -> int4-aligned
    int cntn = deg[n];

    float4 acc = make_float4(0.f, 0.f, 0.f, 0.f);
    for (int i = 0; i < cntn; i += 4) {
        int4 s4 = *(const int4*)(rec + beg + i);
        int rem = cntn - i;
        int i0 = s4.x;
        int i1 = (rem > 1) ? s4.y : i0;
        int i2 = (rem > 2) ? s4.z : i0;
        int i3 = (rem > 3) ? s4.w : i0;
        float n0 = dinv[i0] * dn;
        float n1 = (rem > 1) ? dinv[i1] * dn : 0.f;
        float n2 = (rem > 2) ? dinv[i2] * dn : 0.f;
        float n3 = (rem > 3) ? dinv[i3] * dn : 0.f;
        float4 p0 = *(const float4*)(xwp + (long)i0 * 128 + l4);
        float4 p1 = *(const float4*)(xwp + (long)i1 * 128 + l4);
        float4 p2 = *(const float4*)(xwp + (long)i2 * 128 + l4);
        float4 p3 = *(const float4*)(xwp + (long)i3 * 128 + l4);
        acc.x += n0 * p0.x + n1 * p1.x + n2 * p2.x + n3 * p3.x;
        acc.y += n0 * p0.y + n1 * p1.y + n2 * p2.y + n3 * p3.y;
        acc.z += n0 * p0.z + n1 * p1.z + n2 * p2.z + n3 * p3.z;
        acc.w += n0 * p0.w + n1 * p1.w + n2 * p2.w + n3 * p3.w;
    }
    // self loop
    {
        float d2 = dn * dn;
        float4 ps = *(const float4*)(xwp + (long)n * 128 + l4);
        acc.x += d2 * ps.x;
        acc.y += d2 * ps.y;
        acc.z += d2 * ps.z;
        acc.w += d2 * ps.w;
    }
    // transpose (t,q) -> lane q holds x[t] for its 4 features
    float4 xs[TSTEPS];
#pragma unroll
    for (int t = 0; t < TSTEPS; t++) {
        int srcLane = half * 32 + t * 8 + q;
        xs[t].x = __shfl(acc.x, srcLane, 64);
        xs[t].y = __shfl(acc.y, srcLane, 64);
        xs[t].z = __shfl(acc.z, srcLane, 64);
        xs[t].w = __shfl(acc.w, srcLane, 64);
    }
    if (l < 8) {
        float4 y;
        y.x = (xs[0].x + xs[1].x + xs[2].x + xs[3].x) * 0.25f;
        y.y = (xs[0].y + xs[1].y + xs[2].y + xs[3].y) * 0.25f;
        y.z = (xs[0].z + xs[1].z + xs[2].z + xs[3].z) * 0.25f;
        y.w = (xs[0].w + xs[1].w + xs[2].w + xs[3].w) * 0.25f;
        float4 v = make_float4(0.f, 0.f, 0.f, 0.f);
        int colBase = n * 32 + q * 4;
#pragma unroll
        for (int t = 0; t < TSTEPS; t++) {
            float4 o;
            v.x += xs[t].x; o.x = (v.x >= 1.0f) ? 1.0f : 0.0f; v.x -= o.x;
            v.y += xs[t].y; o.y = (v.y >= 1.0f) ? 1.0f : 0.0f; v.y -= o.y;
            v.z += xs[t].z; o.z = (v.z >= 1.0f) ? 1.0f : 0.0f; v.z -= o.z;
            v.w += xs[t].w; o.w = (v.w >= 1.0f) ? 1.0f : 0.0f; v.w -= o.w;
            *(float4*)(out + (size_t)t * N * 32 + colBase) = o;
        }
        float4 zv = *(const float4*)(z + colBase);
        float4 zn;
        zn.x = zv.x + y.x;
        zn.y = zv.y + y.y;
        zn.z = zv.z + y.z;
        zn.w = zv.w + y.w;
        *(float4*)(out + (size_t)TSTEPS * N * 32 + colBase) = zn;
    }
}

extern "C" void kernel_launch(void* const* d_in, const int* in_sizes, int n_in,
                              void* d_out, int out_size, void* d_ws, size_t ws_size,
                              hipStream_t stream) {
    const float* s_seq = (const float*)d_in[0];
    const float* z_seq = (const float*)d_in[1];
    const float* W     = (const float*)d_in[2];
    const int*   ei    = (const int*)d_in[3];
    float* out = (float*)d_out;

    const int N = in_sizes[1] / DIM;   // 50000
    const int E = in_sizes[3] / 2;     // 800000
    const int rows = TSTEPS * N;       // 200000
    const int nb = (N + 255) >> BINW_SHIFT;   // 196

    // ws layout: xwp | esorted | rec | offs | deg | dinv | ghist | binStart | cursor | recCursor
    char* w = (char*)d_ws;
    float* xwp      = (float*)w;  w += (size_t)rows * DIM * 4;   // 25.6 MB
    int2*  esorted  = (int2*)w;   w += (size_t)E * 8;            // 6.4 MB
    int*   rec      = (int*)w;    w += ((size_t)E + 4 * N) * 4;  // 4.0 MB
    int*   offs     = (int*)w;    w += (size_t)N * 4;
    int*   deg      = (int*)w;    w += (size_t)N * 4;
    float* dinv     = (float*)w;  w += (size_t)N * 4;
    int*   ghist    = (int*)w;    w += NB_MAX * 4;
    int*   binStart = (int*)w;    w += NB_MAX * 4;
    int*   cursor   = (int*)w;    w += NB_MAX * 4;
    int*   recCursor= (int*)w;    w += 16;

    // zero ghist + binStart + cursor + recCursor (contiguous)
    hipMemsetAsync(ghist, 0, NB_MAX * 3 * 4 + 16, stream);

    int hch = (E + HB - 1) / HB;
    int xwBlocks = (rows + 31) / 32;   // 6250
    histxw_kernel<<<HB + xwBlocks, 256, 0, stream>>>(ei, ghist, s_seq, W, xwp,
                                                     E, rows, N, nb, hch);
    scan_kernel<<<1, 256, 0, stream>>>(ghist, binStart, cursor, nb);
    split_kernel<<<(E + K3_CH - 1) / K3_CH, 256, 0, stream>>>(ei, cursor, esorted, E, nb);
    csr_kernel<<<nb, 256, 0, stream>>>(ghist, binStart, esorted, rec, offs, deg,
                                       dinv, recCursor, N);
    gather_kernel<<<(N * 32 + 255) / 256, 256, 0, stream>>>(rec, offs, deg, xwp,
                                                            dinv, z_seq, out, N);
}

// Round 8
// 208.302 us; speedup vs baseline: 1.4009x; 1.0659x over previous
//
#include <hip/hip_runtime.h>

#define TSTEPS 4
#define DIM 32
#define BINW_SHIFT 8          // 256 nodes per coarse bin
#define NB_MAX 256            // max coarse bins (N=50000 -> 196)
#define HB 128                // histogram blocks in K1
#define K3_CH 4096            // edges per K3 block
#define CAPB 4608             // max edges per bin (mean 4096, 8 sigma)

// ---- K1: fused coarse histogram (blocks [0,HB)) + xw GEMM (rest) ----
__global__ __launch_bounds__(256) void histxw_kernel(
    const int* __restrict__ ei, int* __restrict__ ghist,
    const float* __restrict__ s, const float* __restrict__ W, float* __restrict__ xwp,
    int E, int rows, int N, int nb, int hch) {
    __shared__ float sW[32][33];
    __shared__ float sS[32][33];
    __shared__ int lh[NB_MAX];
    int tid = threadIdx.x;
    if ((int)blockIdx.x < HB) {
        for (int b = tid; b < nb; b += 256) lh[b] = 0;
        __syncthreads();
        int beg = blockIdx.x * hch;
        int end = min(beg + hch, E);
        for (int e = beg + tid; e < end; e += 256)
            atomicAdd(&lh[ei[E + e] >> BINW_SHIFT], 1);
        __syncthreads();
        for (int b = tid; b < nb; b += 256)
            if (lh[b]) atomicAdd(&ghist[b], lh[b]);
        return;
    }
    // xw = s @ W, stored node-major: xwp[n*128 + t*32 + c]
    for (int i = tid; i < 1024; i += 256) sW[i >> 5][i & 31] = W[i];
    int rowBase = (blockIdx.x - HB) * 32;
    for (int i = tid; i < 1024; i += 256) {
        int r = rowBase + (i >> 5);
        sS[i >> 5][i & 31] = (r < rows) ? s[r * 32 + (i & 31)] : 0.0f;
    }
    __syncthreads();
    int c = tid & 31;
    for (int rl = tid >> 5; rl < 32; rl += 8) {
        float acc = 0.0f;
#pragma unroll
        for (int k = 0; k < 32; k++) acc += sS[rl][k] * sW[k][c];
        int r = rowBase + rl;
        if (r < rows) {
            int t = r / N;
            int n = r - t * N;
            xwp[n * 128 + t * 32 + c] = acc;
        }
    }
}

// ---- K2: exclusive scan of ghist -> binStart, cursor ----
__global__ __launch_bounds__(256) void scan_kernel(
    const int* __restrict__ ghist, int* __restrict__ binStart,
    int* __restrict__ cursor, int nb) {
    __shared__ int sbuf[256];
    int tid = threadIdx.x;
    int v = (tid < nb) ? ghist[tid] : 0;
    sbuf[tid] = v;
    __syncthreads();
    for (int off = 1; off < 256; off <<= 1) {
        int t = (tid >= off) ? sbuf[tid - off] : 0;
        __syncthreads();
        sbuf[tid] += t;
        __syncthreads();
    }
    if (tid < nb) {
        int excl = sbuf[tid] - v;
        binStart[tid] = excl;
        cursor[tid] = excl;
    }
}

// ---- K3: multisplit. NO register staging (R7 bug: r[16] spilled to scratch,
// 130us of private-mem latency). Two passes over the chunk: hist pass reads
// dst only; place pass reloads src+dst (32KB chunk, L2-hot) ----
__global__ __launch_bounds__(256) void split_kernel(
    const int* __restrict__ ei, int* __restrict__ cursor,
    int2* __restrict__ esorted, int E, int nb) {
    __shared__ int ph[NB_MAX], pscan[NB_MAX], gb[NB_MAX], pcur[NB_MAX];
    __shared__ int2 sbuf[K3_CH];   // 32 KB
    int tid = threadIdx.x;
    int beg = blockIdx.x * K3_CH;
    int end = min(beg + K3_CH, E);
    int cnt = end - beg;
    ph[tid] = 0;   // NB_MAX == blockDim == 256
    __syncthreads();
    // pass A: histogram (dst only)
    for (int e = beg + tid; e < end; e += 256)
        atomicAdd(&ph[ei[E + e] >> BINW_SHIFT], 1);
    __syncthreads();
    // exclusive scan of ph
    int v = ph[tid];
    pscan[tid] = v;
    __syncthreads();
    for (int off = 1; off < 256; off <<= 1) {
        int t = (tid >= off) ? pscan[tid - off] : 0;
        __syncthreads();
        pscan[tid] += t;
        __syncthreads();
    }
    pscan[tid] -= v;                                   // exclusive
    pcur[tid] = pscan[tid];
    gb[tid] = v ? atomicAdd(&cursor[tid], v) : 0;      // bins >= nb have v==0
    __syncthreads();
    // pass B: place into LDS, bin-grouped (reload chunk from L2)
    for (int e = beg + tid; e < end; e += 256) {
        int2 r;
        r.x = ei[e];
        r.y = ei[E + e];
        int b = r.y >> BINW_SHIFT;
        int p = atomicAdd(&pcur[b], 1);
        sbuf[p] = r;
    }
    __syncthreads();
    // write out: contiguous runs per bin, coalesced
    for (int idx = tid; idx < cnt; idx += 256) {
        int2 e = sbuf[idx];
        int b = e.y >> BINW_SHIFT;
        esorted[gb[b] + (idx - pscan[b])] = e;
    }
}

// ---- K4: per-bin exact CSR: counting sort by dst, 16B-padded segments ----
__global__ __launch_bounds__(256) void csr_kernel(
    const int* __restrict__ ghist, const int* __restrict__ binStart,
    const int2* __restrict__ esorted, int* __restrict__ rec,
    int* __restrict__ offs, int* __restrict__ deg, float* __restrict__ dinv,
    int* __restrict__ recCursor, int N) {
    __shared__ int sorted[CAPB + 3 * 256];
    __shared__ int lh[256], loff[256], lcur[256];
    __shared__ int sbase, srun;
    int bin = blockIdx.x;
    int tid = threadIdx.x;
    int nodeBase = bin << BINW_SHIFT;
    int ebeg = binStart[bin];
    int cnt = min(ghist[bin], CAPB);
    lh[tid] = 0;
    __syncthreads();
    for (int i = tid; i < cnt; i += 256)
        atomicAdd(&lh[esorted[ebeg + i].y & 255], 1);
    __syncthreads();
    if (tid == 0) {
        int run = 0;
        for (int i = 0; i < 256; i++) {
            loff[i] = run;
            run += (lh[i] + 3) & ~3;  // 16B-align every node segment
        }
        srun = run;
        sbase = atomicAdd(recCursor, run);
    }
    __syncthreads();
    int run = srun, gbase = sbase;
    for (int i = tid; i < run; i += 256) sorted[i] = 0;  // zero pad slots
    lcur[tid] = 0;
    __syncthreads();
    for (int i = tid; i < cnt; i += 256) {
        int2 e = esorted[ebeg + i];
        int ln = e.y & 255;
        int p = atomicAdd(&lcur[ln], 1);
        sorted[loff[ln] + p] = e.x;
    }
    __syncthreads();
    for (int i = tid; i < run; i += 256) rec[gbase + i] = sorted[i];
    int n = nodeBase + tid;
    if (n < N) {
        offs[n] = gbase + loff[tid];
        deg[n] = lh[tid];
        dinv[n] = rsqrtf((float)lh[tid] + 1.0f);
    }
}

// ---- K5: fused gather + self-loop + mean + IF scan + z_new ----
__global__ __launch_bounds__(256) void gather_kernel(
    const int* __restrict__ rec, const int* __restrict__ offs,
    const int* __restrict__ deg, const float* __restrict__ xwp,
    const float* __restrict__ dinv, const float* __restrict__ z,
    float* __restrict__ out, int N) {
    int gid = blockIdx.x * 256 + threadIdx.x;
    int n = gid >> 5;
    if (n >= N) return;
    int wl = threadIdx.x & 63;
    int half = wl >> 5;
    int l = wl & 31;
    int q = l & 7;
    int l4 = l * 4;

    float dn = dinv[n];
    int beg = offs[n];       // multiple of 4 -> int4-aligned
    int cntn = deg[n];

    float4 acc = make_float4(0.f, 0.f, 0.f, 0.f);
    for (int i = 0; i < cntn; i += 4) {
        int4 s4 = *(const int4*)(rec + beg + i);
        int rem = cntn - i;
        int i0 = s4.x;
        int i1 = (rem > 1) ? s4.y : i0;
        int i2 = (rem > 2) ? s4.z : i0;
        int i3 = (rem > 3) ? s4.w : i0;
        float n0 = dinv[i0] * dn;
        float n1 = (rem > 1) ? dinv[i1] * dn : 0.f;
        float n2 = (rem > 2) ? dinv[i2] * dn : 0.f;
        float n3 = (rem > 3) ? dinv[i3] * dn : 0.f;
        float4 p0 = *(const float4*)(xwp + (long)i0 * 128 + l4);
        float4 p1 = *(const float4*)(xwp + (long)i1 * 128 + l4);
        float4 p2 = *(const float4*)(xwp + (long)i2 * 128 + l4);
        float4 p3 = *(const float4*)(xwp + (long)i3 * 128 + l4);
        acc.x += n0 * p0.x + n1 * p1.x + n2 * p2.x + n3 * p3.x;
        acc.y += n0 * p0.y + n1 * p1.y + n2 * p2.y + n3 * p3.y;
        acc.z += n0 * p0.z + n1 * p1.z + n2 * p2.z + n3 * p3.z;
        acc.w += n0 * p0.w + n1 * p1.w + n2 * p2.w + n3 * p3.w;
    }
    // self loop
    {
        float d2 = dn * dn;
        float4 ps = *(const float4*)(xwp + (long)n * 128 + l4);
        acc.x += d2 * ps.x;
        acc.y += d2 * ps.y;
        acc.z += d2 * ps.z;
        acc.w += d2 * ps.w;
    }
    // transpose (t,q) -> lane q holds x[t] for its 4 features
    float4 xs[TSTEPS];
#pragma unroll
    for (int t = 0; t < TSTEPS; t++) {
        int srcLane = half * 32 + t * 8 + q;
        xs[t].x = __shfl(acc.x, srcLane, 64);
        xs[t].y = __shfl(acc.y, srcLane, 64);
        xs[t].z = __shfl(acc.z, srcLane, 64);
        xs[t].w = __shfl(acc.w, srcLane, 64);
    }
    if (l < 8) {
        float4 y;
        y.x = (xs[0].x + xs[1].x + xs[2].x + xs[3].x) * 0.25f;
        y.y = (xs[0].y + xs[1].y + xs[2].y + xs[3].y) * 0.25f;
        y.z = (xs[0].z + xs[1].z + xs[2].z + xs[3].z) * 0.25f;
        y.w = (xs[0].w + xs[1].w + xs[2].w + xs[3].w) * 0.25f;
        float4 v = make_float4(0.f, 0.f, 0.f, 0.f);
        int colBase = n * 32 + q * 4;
#pragma unroll
        for (int t = 0; t < TSTEPS; t++) {
            float4 o;
            v.x += xs[t].x; o.x = (v.x >= 1.0f) ? 1.0f : 0.0f; v.x -= o.x;
            v.y += xs[t].y; o.y = (v.y >= 1.0f) ? 1.0f : 0.0f; v.y -= o.y;
            v.z += xs[t].z; o.z = (v.z >= 1.0f) ? 1.0f : 0.0f; v.z -= o.z;
            v.w += xs[t].w; o.w = (v.w >= 1.0f) ? 1.0f : 0.0f; v.w -= o.w;
            *(float4*)(out + (size_t)t * N * 32 + colBase) = o;
        }
        float4 zv = *(const float4*)(z + colBase);
        float4 zn;
        zn.x = zv.x + y.x;
        zn.y = zv.y + y.y;
        zn.z = zv.z + y.z;
        zn.w = zv.w + y.w;
        *(float4*)(out + (size_t)TSTEPS * N * 32 + colBase) = zn;
    }
}

extern "C" void kernel_launch(void* const* d_in, const int* in_sizes, int n_in,
                              void* d_out, int out_size, void* d_ws, size_t ws_size,
                              hipStream_t stream) {
    const float* s_seq = (const float*)d_in[0];
    const float* z_seq = (const float*)d_in[1];
    const float* W     = (const float*)d_in[2];
    const int*   ei    = (const int*)d_in[3];
    float* out = (float*)d_out;

    const int N = in_sizes[1] / DIM;   // 50000
    const int E = in_sizes[3] / 2;     // 800000
    const int rows = TSTEPS * N;       // 200000
    const int nb = (N + 255) >> BINW_SHIFT;   // 196

    // ws layout: xwp | esorted | rec | offs | deg | dinv | ghist | binStart | cursor | recCursor
    char* w = (char*)d_ws;
    float* xwp      = (float*)w;  w += (size_t)rows * DIM * 4;   // 25.6 MB
    int2*  esorted  = (int2*)w;   w += (size_t)E * 8;            // 6.4 MB
    int*   rec      = (int*)w;    w += ((size_t)E + 4 * N) * 4;  // 4.0 MB
    int*   offs     = (int*)w;    w += (size_t)N * 4;
    int*   deg      = (int*)w;    w += (size_t)N * 4;
    float* dinv     = (float*)w;  w += (size_t)N * 4;
    int*   ghist    = (int*)w;    w += NB_MAX * 4;
    int*   binStart = (int*)w;    w += NB_MAX * 4;
    int*   cursor   = (int*)w;    w += NB_MAX * 4;
    int*   recCursor= (int*)w;    w += 16;

    // zero ghist + binStart + cursor + recCursor (contiguous)
    hipMemsetAsync(ghist, 0, NB_MAX * 3 * 4 + 16, stream);

    int hch = (E + HB - 1) / HB;
    int xwBlocks = (rows + 31) / 32;   // 6250
    histxw_kernel<<<HB + xwBlocks, 256, 0, stream>>>(ei, ghist, s_seq, W, xwp,
                                                     E, rows, N, nb, hch);
    scan_kernel<<<1, 256, 0, stream>>>(ghist, binStart, cursor, nb);
    split_kernel<<<(E + K3_CH - 1) / K3_CH, 256, 0, stream>>>(ei, cursor, esorted, E, nb);
    csr_kernel<<<nb, 256, 0, stream>>>(ghist, binStart, esorted, rec, offs, deg,
                                       dinv, recCursor, N);
    gather_kernel<<<(N * 32 + 255) / 256, 256, 0, stream>>>(rec, offs, deg, xwp,
                                                            dinv, z_seq, out, N);
}